// Round 5
// baseline (1491.247 us; speedup 1.0000x reference)
//
#include <hip/hip_runtime.h>

#define Bb 64
#define Nn 1024
#define Cc 558
#define CP1 559
#define CPAD 560
#define ITERS 20
#define BLKS_PER_B 4
#define NW 16                  /* waves per block */
#define RPW 16                 /* rows per wave */
#define ROWS_PB 256            /* rows per block */
#define POLL_CAP (1 << 20)

#if __has_builtin(__builtin_amdgcn_rcpf)
#define RCP(x) __builtin_amdgcn_rcpf(x)
#else
#define RCP(x) (1.0f / (x))
#endif

__device__ __forceinline__ float wave_sum(float v) {
#pragma unroll
    for (int off = 32; off > 0; off >>= 1) v += __shfl_xor(v, off, 64);
    return v;
}
__device__ __forceinline__ float wave_max(float v) {
#pragma unroll
    for (int off = 32; off > 0; off >>= 1) v = fmaxf(v, __shfl_xor(v, off, 64));
    return v;
}

__device__ __forceinline__ void g_store(float* p, float v) {
    __hip_atomic_store(p, v, __ATOMIC_RELAXED, __HIP_MEMORY_SCOPE_AGENT);
}
__device__ __forceinline__ float g_load(const float* p) {
    return __hip_atomic_load(p, __ATOMIC_RELAXED, __HIP_MEMORY_SCOPE_AGENT);
}

// ---------------- fp8 e4m3 helpers (values are >= 0 and in normal range) ----------------
#if __has_builtin(__builtin_amdgcn_cvt_pk_fp8_f32) && __has_builtin(__builtin_amdgcn_cvt_pk_f32_fp8)
#define HW_FP8 1
typedef float v2f __attribute__((ext_vector_type(2)));
#endif

__device__ __forceinline__ unsigned enc1_sw(float v) {
    if (!(v > 0.f)) return 0u;
    unsigned u = __float_as_uint(v);
    unsigned t = u + 0x7FFFFu + ((u >> 20) & 1u);   // RNE to 3 mantissa bits
    int e = (int)(t >> 23) - 120;
    if (e < 1) return 0u;                            // flush tiny (outside our range anyway)
    if (e > 15) return 0x7Eu;                        // clamp to 448 (can't happen)
    return ((unsigned)e << 3) | ((t >> 20) & 7u);
}
__device__ __forceinline__ float dec1_sw(unsigned b8) {
    return b8 ? __uint_as_float((((b8 >> 3) + 120u) << 23) | ((b8 & 7u) << 20)) : 0.f;
}
__device__ __forceinline__ unsigned enc4(float f0, float f1, float f2, float f3) {
#ifdef HW_FP8
    int w = 0;
    w = __builtin_amdgcn_cvt_pk_fp8_f32(f0, f1, w, false);
    w = __builtin_amdgcn_cvt_pk_fp8_f32(f2, f3, w, true);
    return (unsigned)w;
#else
    return enc1_sw(f0) | (enc1_sw(f1) << 8) | (enc1_sw(f2) << 16) | (enc1_sw(f3) << 24);
#endif
}
__device__ __forceinline__ void dec4(unsigned w, float& f0, float& f1, float& f2, float& f3) {
#ifdef HW_FP8
    v2f a = __builtin_amdgcn_cvt_pk_f32_fp8((int)w, false);
    v2f b = __builtin_amdgcn_cvt_pk_f32_fp8((int)w, true);
    f0 = a[0]; f1 = a[1]; f2 = b[0]; f3 = b[1];
#else
    f0 = dec1_sw(w & 0xffu); f1 = dec1_sw((w >> 8) & 0xffu);
    f2 = dec1_sw((w >> 16) & 0xffu); f3 = dec1_sw(w >> 24);
#endif
}
__device__ __forceinline__ float dec1(unsigned b8) {
#ifdef HW_FP8
    v2f a = __builtin_amdgcn_cvt_pk_f32_fp8((int)b8, false);
    return a[0];
#else
    return dec1_sw(b8);
#endif
}

// ---- K1: mask-format detect + per-batch mask scan + class-NLL gather ----
__global__ __launch_bounds__(256) void k1_batch(const float* __restrict__ logits,
        const int* __restrict__ labels, const void* __restrict__ maskp,
        float* __restrict__ A_part, float* __restrict__ inv_nvis,
        unsigned char* __restrict__ visc, int* __restrict__ ctr) {
    const int b = blockIdx.x, tid = threadIdx.x;
    __shared__ int sF, sB;
    __shared__ int cs_[256];
    __shared__ float red[256];
    if (tid == 0) { sF = 0; sB = 0; }
    __syncthreads();
    {
        const unsigned int* mw = (const unsigned int*)maskp;
        int lF = 0, lB = 0;
        for (int i = tid; i < (Bb * Nn) / 4; i += 256) {
            unsigned w = mw[i];
            if (w == 0x3F800000u) lF = 1;
            else if (w > 1u) lB = 1;
        }
        if (lF) sF = 1;
        if (lB) sB = 1;
    }
    __syncthreads();
    const int mode = sF ? 2 : (sB ? 1 : 0);   // 0=int32, 1=bool bytes, 2=float32
    int v[4]; int local = 0;
#pragma unroll
    for (int j = 0; j < 4; ++j) {
        const int n = tid * 4 + j;
        const int idx = b * Nn + n;
        int m;
        if (mode == 1)      m = ((const unsigned char*)maskp)[idx] != 0;
        else if (mode == 2) m = ((const float*)maskp)[idx] != 0.f;
        else                m = ((const int*)maskp)[idx] != 0;
        v[j] = m; local += m;
    }
    cs_[tid] = local;
    __syncthreads();
    for (int off = 1; off < 256; off <<= 1) {   // inclusive scan
        int x = 0;
        if (tid >= off) x = cs_[tid - off];
        __syncthreads();
        cs_[tid] += x;
        __syncthreads();
    }
    const int nvis = cs_[255];
    int run = cs_[tid] - local;                  // exclusive prefix
    float nllsum = 0.f;
#pragma unroll
    for (int j = 0; j < 4; ++j) {
        const int n = tid * 4 + j;
        run += v[j];
        visc[b * Nn + n] = (unsigned char)v[j];
        if (v[j]) {
            const int tgt = labels[b * Nn + (run - 1)];
            nllsum -= logits[((size_t)(b * Nn + n)) * Cc + tgt];
        }
    }
    red[tid] = nllsum;
    __syncthreads();
    for (int off = 128; off > 0; off >>= 1) {
        if (tid < off) red[tid] += red[tid + off];
        __syncthreads();
    }
    if (tid == 0) {
        A_part[b] = red[0];
        inv_nvis[b] = 1.f / (float)nvis;
        __hip_atomic_store(&ctr[b], 0, __ATOMIC_RELAXED, __HIP_MEMORY_SCOPE_AGENT);
    }
}

// ---- K_MAIN: persistent; p0 lives in LDS as row-scaled fp8. 256 blocks x 1024 thr,
//      1 block/CU (LDS-capped), 4 blocks per batch, spin-sync between iterations. ----
// Storage permutation: byte (row*560 + 8*lane + k) holds column (64k + lane); tail
// column 512+lane at byte row*560 + 512 + lane. Row scale is EXACTLY neutral for
// Sinkhorn (absorbed into eu; dust entry scaled with the row).
__global__ __launch_bounds__(1024, 4) void k_main(
        const float* __restrict__ logits, const float* __restrict__ dustbin,
        const unsigned char* __restrict__ visc, const float* __restrict__ inv_nvis,
        float* __restrict__ cs, int* __restrict__ ctr,
        float* __restrict__ lse_part, float* __restrict__ ent_part) {
    __shared__ __align__(16) unsigned char q[ROWS_PB * CPAD];   // 143,360 B
    __shared__ float colsum[CPAD];
    __shared__ float evl[CPAD];
    __shared__ float qd[ROWS_PB];        // scaled dust entry per row (0 if invisible)
    __shared__ float eu_l[ROWS_PB];
    __shared__ float redL[NW], redE[NW];
    const int g = blockIdx.x;
    const int b = ((g & 7) << 3) | (g >> 5);   // 4 blocks of a batch on one XCD slot
    const int p = (g >> 3) & 3;
    const int tid = threadIdx.x, wave = tid >> 6, lane = tid & 63;
    const int lrow0 = wave << 4;               // block-local first row of this wave
    const int grow0 = (b << 10) + (p << 8) + lrow0;
    const float dustp = __expf(dustbin[0]);
    const float invn = inv_nvis[b];
    const bool tl = lane < 46;

    const uint4 vA = *(const uint4*)(visc + grow0);
    const unsigned vw[4] = {vA.x, vA.y, vA.z, vA.w};
#define VISB(r) ((vw[(r) >> 2] >> (((r) & 3) << 3)) & 0xffu)

    float lsesum = 0.f;

    // ---------- softmax -> scaled fp8 into LDS (logits read ONCE, never again) ----------
#pragma unroll
    for (int r = 0; r < RPW; ++r) {
        unsigned long long* dst =
            (unsigned long long*)(q + (lrow0 + r) * CPAD + (lane << 3));
        if (__builtin_amdgcn_readfirstlane(VISB(r))) {
            const float* rowp = logits + (size_t)(grow0 + r) * Cc;
            const float e0 = __expf(rowp[lane]);
            const float e1 = __expf(rowp[64 + lane]);
            const float e2 = __expf(rowp[128 + lane]);
            const float e3 = __expf(rowp[192 + lane]);
            const float e4 = __expf(rowp[256 + lane]);
            const float e5 = __expf(rowp[320 + lane]);
            const float e6 = __expf(rowp[384 + lane]);
            const float e7 = __expf(rowp[448 + lane]);
            float et = 0.f;
            if (tl) et = __expf(rowp[512 + lane]);
            float mx = fmaxf(fmaxf(fmaxf(e0, e1), fmaxf(e2, e3)),
                             fmaxf(fmaxf(e4, e5), fmaxf(e6, e7)));
            mx = wave_max(fmaxf(mx, et));
            const float s = wave_sum(e0 + e1 + e2 + e3 + e4 + e5 + e6 + e7 + et);
            // q_c = p_c * scale_row, scale_row = 416*s/mx  =>  q_c = e_c * 416/mx
            const float fm = 416.f * RCP(mx);
            const unsigned w0 = enc4(e0 * fm, e1 * fm, e2 * fm, e3 * fm);
            const unsigned w1 = enc4(e4 * fm, e5 * fm, e6 * fm, e7 * fm);
            *dst = (unsigned long long)w0 | ((unsigned long long)w1 << 32);
            if (tl) q[(lrow0 + r) * CPAD + 512 + lane] =
                        (unsigned char)(enc4(et * fm, 0.f, 0.f, 0.f) & 0xffu);
            if (lane == 0) qd[lrow0 + r] = dustp * fm * s;   // dust entry, same row scale
            lsesum += __logf(s);
        } else {
            *dst = 0ull;
            if (tl) q[(lrow0 + r) * CPAD + 512 + lane] = 0;
            if (lane == 0) qd[lrow0 + r] = 0.f;
        }
    }
    __syncthreads();

    // ---------- 20 Sinkhorn iterations, p0 read from LDS only ----------
    for (int t = 0; t < ITERS; ++t) {
        if (tid < CP1) {
            colsum[tid] = 0.f;
            float ev = 1.f;                      // iter 0: v=0 -> ev=1
            if (t) {
                const float* CSr =
                    cs + (size_t)(((t - 1) & 1) * Bb + b) * (BLKS_PER_B * CPAD) + tid;
                ev = RCP(559.f * (g_load(CSr) + g_load(CSr + CPAD)
                                + g_load(CSr + 2 * CPAD) + g_load(CSr + 3 * CPAD)));
            }
            evl[tid] = ev;
        }
        __syncthreads();
        const float evr0 = evl[lane],        evr1 = evl[64 + lane];
        const float evr2 = evl[128 + lane],  evr3 = evl[192 + lane];
        const float evr4 = evl[256 + lane],  evr5 = evl[320 + lane];
        const float evr6 = evl[384 + lane],  evr7 = evl[448 + lane];
        const float evt = tl ? evl[512 + lane] : 0.f;
        const float evd = evl[558];
        const bool lastw = (t == ITERS - 1);
        float pc0 = 0.f, pc1 = 0.f, pc2 = 0.f, pc3 = 0.f;
        float pc4 = 0.f, pc5 = 0.f, pc6 = 0.f, pc7 = 0.f;
        float pct = 0.f, pcd = 0.f;
#pragma unroll
        for (int r = 0; r < RPW; ++r) {
            const unsigned long long wq =
                *(const unsigned long long*)(q + (lrow0 + r) * CPAD + (lane << 3));
            float f0, f1, f2, f3, f4, f5, f6, f7;
            dec4((unsigned)wq, f0, f1, f2, f3);
            dec4((unsigned)(wq >> 32), f4, f5, f6, f7);
            float xt = 0.f;
            if (tl) xt = dec1(q[(lrow0 + r) * CPAD + 512 + lane]);
            const float qdr = qd[lrow0 + r];     // LDS broadcast
            float s = f0 * evr0 + f1 * evr1 + f2 * evr2 + f3 * evr3
                    + f4 * evr4 + f5 * evr5 + f6 * evr6 + f7 * evr7 + xt * evt;
            s = wave_sum(s) + qdr * evd;
            const float euv = VISB(r) ? invn * RCP(s) : 0.f;
            if (lastw && lane == 0) eu_l[lrow0 + r] = euv;
            pc0 += f0 * euv; pc1 += f1 * euv; pc2 += f2 * euv; pc3 += f3 * euv;
            pc4 += f4 * euv; pc5 += f5 * euv; pc6 += f6 * euv; pc7 += f7 * euv;
            pct += xt * euv; pcd += qdr * euv;
        }
        atomicAdd(&colsum[lane], pc0);        atomicAdd(&colsum[64 + lane], pc1);
        atomicAdd(&colsum[128 + lane], pc2);  atomicAdd(&colsum[192 + lane], pc3);
        atomicAdd(&colsum[256 + lane], pc4);  atomicAdd(&colsum[320 + lane], pc5);
        atomicAdd(&colsum[384 + lane], pc6);  atomicAdd(&colsum[448 + lane], pc7);
        if (tl) atomicAdd(&colsum[512 + lane], pct);
        if (lane == 0) atomicAdd(&colsum[558], pcd);
        __syncthreads();
        float* CSw = cs + (size_t)(((t & 1) * Bb + b) * BLKS_PER_B + p) * CPAD;
        if (tid < CP1) g_store(CSw + tid, colsum[tid]);
        __syncthreads();   // drains the global stores (vmcnt 0 at barrier)
        if (tid == 0) {
            __hip_atomic_fetch_add(&ctr[b], 1, __ATOMIC_RELEASE, __HIP_MEMORY_SCOPE_AGENT);
            const int target = BLKS_PER_B * (t + 1);
            int polls = 0;
            while (__hip_atomic_load(&ctr[b], __ATOMIC_ACQUIRE,
                                     __HIP_MEMORY_SCOPE_AGENT) < target) {
                __builtin_amdgcn_s_sleep(1);
                if (++polls > POLL_CAP) break;   // fail-visible, never hang
            }
        }
        __syncthreads();
    }

    // ---------- final ev + entropy (P = eu'*q*ev is the TRUE plan; scales cancel) ----------
    if (tid < CP1) {
        const float* CSr =
            cs + (size_t)(((ITERS - 1) & 1) * Bb + b) * (BLKS_PER_B * CPAD) + tid;
        evl[tid] = RCP(559.f * (g_load(CSr) + g_load(CSr + CPAD)
                              + g_load(CSr + 2 * CPAD) + g_load(CSr + 3 * CPAD)));
    }
    __syncthreads();
    {
        const float evr0 = evl[lane],        evr1 = evl[64 + lane];
        const float evr2 = evl[128 + lane],  evr3 = evl[192 + lane];
        const float evr4 = evl[256 + lane],  evr5 = evl[320 + lane];
        const float evr6 = evl[384 + lane],  evr7 = evl[448 + lane];
        const float evt = tl ? evl[512 + lane] : 0.f;
        float acc = 0.f;
#pragma unroll
        for (int r = 0; r < RPW; ++r) {
            const float euv = eu_l[lrow0 + r];
            const unsigned long long wq =
                *(const unsigned long long*)(q + (lrow0 + r) * CPAD + (lane << 3));
            float f0, f1, f2, f3, f4, f5, f6, f7;
            dec4((unsigned)wq, f0, f1, f2, f3);
            dec4((unsigned)(wq >> 32), f4, f5, f6, f7);
            float xt = 0.f;
            if (tl) xt = dec1(q[(lrow0 + r) * CPAD + 512 + lane]);
            float P;
            P = f0 * euv * evr0; acc -= P * __logf(P + 1e-8f);
            P = f1 * euv * evr1; acc -= P * __logf(P + 1e-8f);
            P = f2 * euv * evr2; acc -= P * __logf(P + 1e-8f);
            P = f3 * euv * evr3; acc -= P * __logf(P + 1e-8f);
            P = f4 * euv * evr4; acc -= P * __logf(P + 1e-8f);
            P = f5 * euv * evr5; acc -= P * __logf(P + 1e-8f);
            P = f6 * euv * evr6; acc -= P * __logf(P + 1e-8f);
            P = f7 * euv * evr7; acc -= P * __logf(P + 1e-8f);
            P = xt * euv * evt;  acc -= P * __logf(P + 1e-8f);
        }
        acc = wave_sum(acc);
        if (lane == 0) { redE[wave] = acc; redL[wave] = lsesum; }
    }
    __syncthreads();
    if (tid == 0) {
        float eS = 0.f, lS = 0.f;
#pragma unroll
        for (int w = 0; w < NW; ++w) { eS += redE[w]; lS += redL[w]; }
        ent_part[(b << 2) | p] = eS;
        lse_part[(b << 2) | p] = lS;
    }
}

// ---- K4: combine ----
__global__ void k4_out(const float* __restrict__ A_part, const float* __restrict__ lse_part,
        const float* __restrict__ ent_part, const float* __restrict__ inv_nvis,
        float* __restrict__ out) {
    const int b = threadIdx.x;   // 64 threads = 1 wave
    float l = 0.f, e = 0.f;
#pragma unroll
    for (int p = 0; p < BLKS_PER_B; ++p) {
        l += lse_part[(b << 2) | p];
        e += ent_part[(b << 2) | p];
    }
    float v = (A_part[b] + l) * inv_nvis[b] + 0.5f * e * inv_nvis[b];
    v = wave_sum(v);
    if (b == 0) out[0] = v * (1.f / 64.f);
}

extern "C" void kernel_launch(void* const* d_in, const int* in_sizes, int n_in,
                              void* d_out, int out_size, void* d_ws, size_t ws_size,
                              hipStream_t stream) {
    const float* logits = (const float*)d_in[0];
    const float* dustbin = (const float*)d_in[1];
    const int* labels = (const int*)d_in[2];
    const void* mask = d_in[3];
    float* out = (float*)d_out;

    char* ws = (char*)d_ws;
    size_t off = 0;
    float* cs = (float*)(ws + off);            off += 2ull * Bb * BLKS_PER_B * CPAD * 4;
    int* ctr = (int*)(ws + off);               off += Bb * 4;
    unsigned char* visc = (unsigned char*)(ws + off); off += (size_t)Bb * Nn;
    float* inv_nvis = (float*)(ws + off);      off += Bb * 4;
    float* A_part = (float*)(ws + off);        off += Bb * 4;
    float* lse_part = (float*)(ws + off);      off += Bb * BLKS_PER_B * 4;
    float* ent_part = (float*)(ws + off);      off += Bb * BLKS_PER_B * 4;

    k1_batch<<<Bb, 256, 0, stream>>>(logits, labels, mask, A_part, inv_nvis, visc, ctr);
    k_main<<<Bb * BLKS_PER_B, 1024, 0, stream>>>(logits, dustbin, visc, inv_nvis,
                                                 cs, ctr, lse_part, ent_part);
    k4_out<<<1, 64, 0, stream>>>(A_part, lse_part, ent_part, inv_nvis, out);
    (void)in_sizes; (void)n_in; (void)out_size; (void)ws_size;
}

// Round 6
// 572.718 us; speedup vs baseline: 2.6038x; 2.6038x over previous
//
#include <hip/hip_runtime.h>

#define Bb 64
#define Nn 1024
#define Cc 558
#define CP1 559
#define CPAD 560
#define ITERS 20
#define PBLK 8                 /* blocks per batch in k2/k3 */
#define RPB (Nn/PBLK)          /* 128 rows per block */
#define WAVES 8
#define RPW (RPB/WAVES)        /* 16 rows per wave */
#define BLOCK 512

#if __has_builtin(__builtin_amdgcn_rcpf)
#define RCP(x) __builtin_amdgcn_rcpf(x)
#else
#define RCP(x) (1.0f / (x))
#endif

__device__ __forceinline__ float wave_sum(float v) {
#pragma unroll
    for (int off = 32; off > 0; off >>= 1) v += __shfl_xor(v, off, 64);
    return v;
}
__device__ __forceinline__ float wave_max(float v) {
#pragma unroll
    for (int off = 32; off > 0; off >>= 1) v = fmaxf(v, __shfl_xor(v, off, 64));
    return v;
}

// ---------------- fp8 e4m3 helpers (values >= 0, normal range; HW-validated in R5) ----
#if __has_builtin(__builtin_amdgcn_cvt_pk_fp8_f32) && __has_builtin(__builtin_amdgcn_cvt_pk_f32_fp8)
#define HW_FP8 1
typedef float v2f __attribute__((ext_vector_type(2)));
#endif

__device__ __forceinline__ unsigned enc1_sw(float v) {
    if (!(v > 0.f)) return 0u;
    unsigned u = __float_as_uint(v);
    unsigned t = u + 0x7FFFFu + ((u >> 20) & 1u);   // RNE to 3 mantissa bits
    int e = (int)(t >> 23) - 120;
    if (e < 1) return 0u;
    if (e > 15) return 0x7Eu;
    return ((unsigned)e << 3) | ((t >> 20) & 7u);
}
__device__ __forceinline__ float dec1_sw(unsigned b8) {
    return b8 ? __uint_as_float((((b8 >> 3) + 120u) << 23) | ((b8 & 7u) << 20)) : 0.f;
}
__device__ __forceinline__ unsigned enc4(float f0, float f1, float f2, float f3) {
#ifdef HW_FP8
    int w = 0;
    w = __builtin_amdgcn_cvt_pk_fp8_f32(f0, f1, w, false);
    w = __builtin_amdgcn_cvt_pk_fp8_f32(f2, f3, w, true);
    return (unsigned)w;
#else
    return enc1_sw(f0) | (enc1_sw(f1) << 8) | (enc1_sw(f2) << 16) | (enc1_sw(f3) << 24);
#endif
}
__device__ __forceinline__ void dec4(unsigned w, float& f0, float& f1, float& f2, float& f3) {
#ifdef HW_FP8
    v2f a = __builtin_amdgcn_cvt_pk_f32_fp8((int)w, false);
    v2f b = __builtin_amdgcn_cvt_pk_f32_fp8((int)w, true);
    f0 = a[0]; f1 = a[1]; f2 = b[0]; f3 = b[1];
#else
    f0 = dec1_sw(w & 0xffu); f1 = dec1_sw((w >> 8) & 0xffu);
    f2 = dec1_sw((w >> 16) & 0xffu); f3 = dec1_sw(w >> 24);
#endif
}
__device__ __forceinline__ float dec1(unsigned b8) {
#ifdef HW_FP8
    v2f a = __builtin_amdgcn_cvt_pk_f32_fp8((int)b8, false);
    return a[0];
#else
    return dec1_sw(b8);
#endif
}

// ---- K0: per-row softmax -> row-scaled fp8 q + lse + scaled dust entry qd ----
// Storage: byte row*560 + 8*lane + k holds column 64k+lane (k=0..7);
//          byte row*560 + 512 + lane holds column 512+lane (lane<46).
__global__ __launch_bounds__(256) void k0_softmax(const float* __restrict__ logits,
        const float* __restrict__ dustbin, unsigned char* __restrict__ p8,
        float* __restrict__ qd, float* __restrict__ lse) {
    const int wave = threadIdx.x >> 6, lane = threadIdx.x & 63;
    const int r = (blockIdx.x << 2) + wave;
    const float* rowp = logits + (size_t)r * Cc;
    const bool tl = lane < 46;
    const float e0 = __expf(rowp[lane]);
    const float e1 = __expf(rowp[64 + lane]);
    const float e2 = __expf(rowp[128 + lane]);
    const float e3 = __expf(rowp[192 + lane]);
    const float e4 = __expf(rowp[256 + lane]);
    const float e5 = __expf(rowp[320 + lane]);
    const float e6 = __expf(rowp[384 + lane]);
    const float e7 = __expf(rowp[448 + lane]);
    float et = 0.f;
    if (tl) et = __expf(rowp[512 + lane]);
    float mx = fmaxf(fmaxf(fmaxf(e0, e1), fmaxf(e2, e3)),
                     fmaxf(fmaxf(e4, e5), fmaxf(e6, e7)));
    mx = wave_max(fmaxf(mx, et));
    const float s = wave_sum(e0 + e1 + e2 + e3 + e4 + e5 + e6 + e7 + et);
    const float fm = 416.f * RCP(mx);            // q_c = e_c*fm = p_c*(fm*s)
    const unsigned w0 = enc4(e0 * fm, e1 * fm, e2 * fm, e3 * fm);
    const unsigned w1 = enc4(e4 * fm, e5 * fm, e6 * fm, e7 * fm);
    unsigned char* rowq = p8 + (size_t)r * CPAD;
    *(unsigned long long*)(rowq + (lane << 3)) =
        (unsigned long long)w0 | ((unsigned long long)w1 << 32);
    if (tl) rowq[512 + lane] = (unsigned char)(enc4(et * fm, 0.f, 0.f, 0.f) & 0xffu);
    if (lane == 0) {
        qd[r] = __expf(dustbin[0]) * fm * s;     // dust entry, same row scale
        lse[r] = __logf(s);
    }
}

// ---- K1: mask-format detect + per-batch mask scan + class loss (R1-proven) ----
__global__ __launch_bounds__(256) void k1_batch(const float* __restrict__ logits,
        const int* __restrict__ labels, const void* __restrict__ maskp,
        const float* __restrict__ lse, float* __restrict__ class_part,
        float* __restrict__ inv_nvis, unsigned char* __restrict__ visc) {
    const int b = blockIdx.x, tid = threadIdx.x;
    __shared__ int sF, sB;
    __shared__ int cs_[256];
    __shared__ float red[256];
    if (tid == 0) { sF = 0; sB = 0; }
    __syncthreads();
    {
        const unsigned int* mw = (const unsigned int*)maskp;
        int lF = 0, lB = 0;
        for (int i = tid; i < (Bb * Nn) / 4; i += 256) {
            unsigned w = mw[i];
            if (w == 0x3F800000u) lF = 1;
            else if (w > 1u) lB = 1;
        }
        if (lF) sF = 1;
        if (lB) sB = 1;
    }
    __syncthreads();
    const int mode = sF ? 2 : (sB ? 1 : 0);   // 0=int32, 1=bool bytes, 2=float32
    int v[4]; int local = 0;
#pragma unroll
    for (int j = 0; j < 4; ++j) {
        const int n = tid * 4 + j;
        const int idx = b * Nn + n;
        int m;
        if (mode == 1)      m = ((const unsigned char*)maskp)[idx] != 0;
        else if (mode == 2) m = ((const float*)maskp)[idx] != 0.f;
        else                m = ((const int*)maskp)[idx] != 0;
        v[j] = m; local += m;
    }
    cs_[tid] = local;
    __syncthreads();
    for (int off = 1; off < 256; off <<= 1) {   // inclusive scan
        int x = 0;
        if (tid >= off) x = cs_[tid - off];
        __syncthreads();
        cs_[tid] += x;
        __syncthreads();
    }
    const int nvis = cs_[255];
    int run = cs_[tid] - local;                  // exclusive prefix
    float nllsum = 0.f;
#pragma unroll
    for (int j = 0; j < 4; ++j) {
        const int n = tid * 4 + j;
        run += v[j];
        visc[b * Nn + n] = (unsigned char)v[j];
        if (v[j]) {
            const int tgt = labels[b * Nn + (run - 1)];
            nllsum += lse[b * Nn + n] - logits[((size_t)(b * Nn + n)) * Cc + tgt];
        }
    }
    red[tid] = nllsum;
    __syncthreads();
    for (int off = 128; off > 0; off >>= 1) {
        if (tid < off) red[tid] += red[tid + off];
        __syncthreads();
    }
    if (tid == 0) {
        class_part[b] = red[0] / (float)nvis;
        inv_nvis[b] = 1.f / (float)nvis;
    }
}

// ---- K2: one fused Sinkhorn iteration (row update + column partial sums), fp8 ----
__global__ __launch_bounds__(BLOCK) void k2_iter(const unsigned char* __restrict__ p8,
        const float* __restrict__ qd, const unsigned char* __restrict__ visc,
        const float* __restrict__ inv_nvis, float* __restrict__ eu_g,
        const float* __restrict__ Rp, float* __restrict__ Wp, const int first) {
    __shared__ float evl[CPAD];
    __shared__ float partl[WAVES][CPAD];
    const int b = blockIdx.x >> 3, p = blockIdx.x & 7, tid = threadIdx.x;
    const int wave = tid >> 6, lane = tid & 63;
    for (int c = tid; c < CP1; c += BLOCK) {
        float ev = 1.f;                          // iteration 1: v = 0 => ev = 1
        if (!first) {
            const float* CSr = Rp + (size_t)(b * PBLK) * CPAD + c;
            float s = 0.f;
#pragma unroll
            for (int q = 0; q < PBLK; ++q) s += CSr[q * CPAD];
            ev = RCP(559.f * s);
        }
        evl[c] = ev;
    }
    __syncthreads();
    const bool tl = lane < 46;
    const float evr0 = evl[lane],        evr1 = evl[64 + lane];
    const float evr2 = evl[128 + lane],  evr3 = evl[192 + lane];
    const float evr4 = evl[256 + lane],  evr5 = evl[320 + lane];
    const float evr6 = evl[384 + lane],  evr7 = evl[448 + lane];
    const float evt = tl ? evl[512 + lane] : 0.f;
    const float evd = evl[558];
    const float invn = inv_nvis[b];
    const int row0 = (b << 10) + (p << 7) + (wave << 4);
    const uint4 vA = *(const uint4*)(visc + row0);
    const unsigned vw[4] = {vA.x, vA.y, vA.z, vA.w};
#define VISB(r) ((vw[(r) >> 2] >> (((r) & 3) << 3)) & 0xffu)
    float pc0 = 0.f, pc1 = 0.f, pc2 = 0.f, pc3 = 0.f;
    float pc4 = 0.f, pc5 = 0.f, pc6 = 0.f, pc7 = 0.f;
    float pct = 0.f, pcd = 0.f;
#pragma unroll
    for (int r = 0; r < RPW; ++r) {
        const unsigned char* rowq = p8 + (size_t)(row0 + r) * CPAD;
        const unsigned long long wq = *(const unsigned long long*)(rowq + (lane << 3));
        float f0, f1, f2, f3, f4, f5, f6, f7;
        dec4((unsigned)wq, f0, f1, f2, f3);
        dec4((unsigned)(wq >> 32), f4, f5, f6, f7);
        float xt = 0.f;
        if (tl) xt = dec1(rowq[512 + lane]);
        const float qdr = qd[row0 + r];
        float s = f0 * evr0 + f1 * evr1 + f2 * evr2 + f3 * evr3
                + f4 * evr4 + f5 * evr5 + f6 * evr6 + f7 * evr7 + xt * evt;
        s = wave_sum(s) + qdr * evd;
        const float euv = VISB(r) ? invn * RCP(s) : 0.f;   // invisible row: eu = 0
        if (lane == 0) eu_g[row0 + r] = euv;
        pc0 += f0 * euv; pc1 += f1 * euv; pc2 += f2 * euv; pc3 += f3 * euv;
        pc4 += f4 * euv; pc5 += f5 * euv; pc6 += f6 * euv; pc7 += f7 * euv;
        pct += xt * euv; pcd += qdr * euv;     // (dust·S_r)·(eu/S_r) = exact dust colsum
    }
    // strided ownership: consecutive lanes -> consecutive banks, conflict-free
    partl[wave][lane] = pc0;        partl[wave][64 + lane] = pc1;
    partl[wave][128 + lane] = pc2;  partl[wave][192 + lane] = pc3;
    partl[wave][256 + lane] = pc4;  partl[wave][320 + lane] = pc5;
    partl[wave][384 + lane] = pc6;  partl[wave][448 + lane] = pc7;
    if (tl) partl[wave][512 + lane] = pct;
    if (lane == 0) partl[wave][558] = pcd;
    __syncthreads();
    float* CSw = Wp + (size_t)(b * PBLK + p) * CPAD;
    for (int c = tid; c < CP1; c += BLOCK) {
        CSw[c] = partl[0][c] + partl[1][c] + partl[2][c] + partl[3][c]
               + partl[4][c] + partl[5][c] + partl[6][c] + partl[7][c];
    }
}

// ---- K3: entropy of final plan (excludes dustbin column) ----
__global__ __launch_bounds__(BLOCK) void k3_final(const unsigned char* __restrict__ p8,
        const float* __restrict__ eu_g, const float* __restrict__ Rp,
        const float* __restrict__ inv_nvis, float* __restrict__ assign_part) {
    __shared__ float evl[CPAD];
    __shared__ float red[WAVES];
    const int b = blockIdx.x >> 3, p = blockIdx.x & 7, tid = threadIdx.x;
    const int wave = tid >> 6, lane = tid & 63;
    for (int c = tid; c < CP1; c += BLOCK) {
        const float* CSr = Rp + (size_t)(b * PBLK) * CPAD + c;
        float s = 0.f;
#pragma unroll
        for (int q = 0; q < PBLK; ++q) s += CSr[q * CPAD];
        evl[c] = RCP(559.f * s);
    }
    __syncthreads();
    const bool tl = lane < 46;
    const float evr0 = evl[lane],        evr1 = evl[64 + lane];
    const float evr2 = evl[128 + lane],  evr3 = evl[192 + lane];
    const float evr4 = evl[256 + lane],  evr5 = evl[320 + lane];
    const float evr6 = evl[384 + lane],  evr7 = evl[448 + lane];
    const float evt = tl ? evl[512 + lane] : 0.f;
    const int row0 = (b << 10) + (p << 7) + (wave << 4);
    float acc = 0.f;
#pragma unroll
    for (int r = 0; r < RPW; ++r) {
        const float euv = eu_g[row0 + r];        // 0 for invisible rows
        const unsigned char* rowq = p8 + (size_t)(row0 + r) * CPAD;
        const unsigned long long wq = *(const unsigned long long*)(rowq + (lane << 3));
        float f0, f1, f2, f3, f4, f5, f6, f7;
        dec4((unsigned)wq, f0, f1, f2, f3);
        dec4((unsigned)(wq >> 32), f4, f5, f6, f7);
        float xt = 0.f;
        if (tl) xt = dec1(rowq[512 + lane]);
        float P;
        P = f0 * euv * evr0; acc -= P * __logf(P + 1e-8f);
        P = f1 * euv * evr1; acc -= P * __logf(P + 1e-8f);
        P = f2 * euv * evr2; acc -= P * __logf(P + 1e-8f);
        P = f3 * euv * evr3; acc -= P * __logf(P + 1e-8f);
        P = f4 * euv * evr4; acc -= P * __logf(P + 1e-8f);
        P = f5 * euv * evr5; acc -= P * __logf(P + 1e-8f);
        P = f6 * euv * evr6; acc -= P * __logf(P + 1e-8f);
        P = f7 * euv * evr7; acc -= P * __logf(P + 1e-8f);
        P = xt * euv * evt;  acc -= P * __logf(P + 1e-8f);
    }
    acc = wave_sum(acc);
    if (lane == 0) red[wave] = acc;
    __syncthreads();
    if (tid == 0) {
        float s = 0.f;
#pragma unroll
        for (int w = 0; w < WAVES; ++w) s += red[w];
        assign_part[blockIdx.x] = s * inv_nvis[b];
    }
}

// ---- K4: combine ----
__global__ void k4_out(const float* __restrict__ class_part,
                       const float* __restrict__ assign_part, float* __restrict__ out) {
    const int b = threadIdx.x;   // 64 threads = 1 wave
    float v = class_part[b];
    float a = 0.f;
#pragma unroll
    for (int p = 0; p < PBLK; ++p) a += assign_part[b * PBLK + p];
    v += 0.5f * a;
    v = wave_sum(v);
    if (b == 0) out[0] = v * (1.f / 64.f);
}

extern "C" void kernel_launch(void* const* d_in, const int* in_sizes, int n_in,
                              void* d_out, int out_size, void* d_ws, size_t ws_size,
                              hipStream_t stream) {
    const float* logits = (const float*)d_in[0];
    const float* dustbin = (const float*)d_in[1];
    const int* labels = (const int*)d_in[2];
    const void* mask = d_in[3];
    float* out = (float*)d_out;

    char* ws = (char*)d_ws;
    size_t off = 0;
    unsigned char* p8 = (unsigned char*)(ws + off); off += (size_t)Bb * Nn * CPAD;  // 36.7 MB
    float* qd = (float*)(ws + off);            off += (size_t)Bb * Nn * 4;
    float* lse = (float*)(ws + off);           off += (size_t)Bb * Nn * 4;
    float* eu_g = (float*)(ws + off);          off += (size_t)Bb * Nn * 4;
    unsigned char* visc = (unsigned char*)(ws + off); off += (size_t)Bb * Nn;
    float* inv_nvis = (float*)(ws + off);      off += Bb * 4;
    float* parts = (float*)(ws + off);         off += 2ull * Bb * PBLK * CPAD * 4;
    float* class_part = (float*)(ws + off);    off += Bb * 4;
    float* assign_part = (float*)(ws + off);   off += Bb * PBLK * 4;
    const size_t SLOT = (size_t)Bb * PBLK * CPAD;  // floats per parts buffer

    k0_softmax<<<(Bb * Nn) / 4, 256, 0, stream>>>(logits, dustbin, p8, qd, lse);
    k1_batch<<<Bb, 256, 0, stream>>>(logits, labels, mask, lse,
                                     class_part, inv_nvis, visc);
    for (int t = 0; t < ITERS; ++t) {
        float* Wb = parts + (size_t)(t & 1) * SLOT;
        const float* Rb = parts + (size_t)((t + 1) & 1) * SLOT;
        k2_iter<<<Bb * PBLK, BLOCK, 0, stream>>>(p8, qd, visc, inv_nvis, eu_g, Rb, Wb,
                                                 (t == 0) ? 1 : 0);
    }
    k3_final<<<Bb * PBLK, BLOCK, 0, stream>>>(p8, eu_g,
            parts + (size_t)((ITERS - 1) & 1) * SLOT, inv_nvis, assign_part);
    k4_out<<<1, 64, 0, stream>>>(class_part, assign_part, out);
    (void)in_sizes; (void)n_in; (void)out_size; (void)ws_size;
}